// Round 2
// baseline (726.440 us; speedup 1.0000x reference)
//
#include <hip/hip_runtime.h>
#include <math.h>

constexpr int HWPIX   = 4096;   // 64*64 pixels per image
constexpr int BLK     = 256;
constexpr int ABLOCKS = 2048;   // grid-stride streamer, ~8 blocks/CU

// ======================================================================
// Kernel A: pure memcpy-shaped stream over x -> compact byte mask in ws.
// mask[p] = (ch1==1) | (ch3==1)<<1  for pixel p (global, row-major).
// Shape mirrors the fill/copy kernels that sustain 6.2+ TB/s in this
// trace: grid-stride, unit-stride per wave, no LDS, no barriers, no
// per-image partitioning. Entry e (float4) parity == thread parity, so
// even lanes always hold the ch0-3 half of a pixel.
// ======================================================================
__global__ __launch_bounds__(BLK) void compress_kernel(
    const float4* __restrict__ x4,
    unsigned char* __restrict__ mask,
    const long long n4)
{
    const long long NT = (long long)gridDim.x * BLK;
    const bool even    = ((threadIdx.x & 1) == 0);
    long long e = (long long)blockIdx.x * BLK + threadIdx.x;

    for (; e + 7 * NT < n4; e += 8 * NT) {
        float4 v[8];
        #pragma unroll
        for (int j = 0; j < 8; ++j)
            v[j] = x4[e + (long long)j * NT];
        if (even) {
            #pragma unroll
            for (int j = 0; j < 8; ++j) {
                const long long ee = e + (long long)j * NT;
                const unsigned char m =
                    (unsigned char)((v[j].y == 1.0f ? 1u : 0u) |
                                    (v[j].w == 1.0f ? 2u : 0u));
                mask[ee >> 1] = m;
            }
        }
    }
    for (; e < n4; e += NT) {        // tail (empty for B=4096)
        const float4 v = x4[e];
        if (even)
            mask[e >> 1] = (unsigned char)((v.y == 1.0f ? 1u : 0u) |
                                           (v.w == 1.0f ? 2u : 0u));
    }
}

// ======================================================================
// Kernel B: per-image logic from the 4 KiB mask (L2/LLC-resident).
// Reduction / decision / store phases are the verified R0 code verbatim;
// only the food/opp source changed (mask bytes instead of x).
// ======================================================================
__global__ __launch_bounds__(BLK) void oracle_kernel(
    const unsigned char* __restrict__ mask,
    const float* __restrict__ opp_start,
    float* __restrict__ out)
{
    const int b    = blockIdx.x;
    const int t    = threadIdx.x;
    const int lane = t & 63;
    const int wv   = t >> 6;   // wave id 0..3

    __shared__ unsigned char s_food[HWPIX];  // 4 KiB food-only byte mask
    __shared__ int   s_stat[4][3];           // per-wave: food_cnt, opp_cnt, first_opp
    __shared__ float s_m1[4], s_m2[4];
    __shared__ int   s_i1[4];
    __shared__ int   s_hdr[3];               // n_food, n_opp, first_opp
    __shared__ int   s_dec[3];               // ambiguous, pick_nearest, min_idx

    // ---- Phase 1: load this image's mask (4 KiB), 16 pixels/thread -----
    const uint4* mb = (const uint4*)(mask + (size_t)b * HWPIX);
    const uint4 w = mb[t];                   // bytes 16t .. 16t+15
    unsigned md[4] = { w.x, w.y, w.z, w.w };
    unsigned fd[4], od[4];
    #pragma unroll
    for (int j = 0; j < 4; ++j) {
        fd[j] = md[j] & 0x01010101u;         // food bytes
        od[j] = md[j] & 0x02020202u;         // opp bytes
    }
    // publish food-only bytes to LDS for phases 2/3
    ((uint4*)s_food)[t] = make_uint4(fd[0], fd[1], fd[2], fd[3]);

    int fc = 0, oc = 0, fo = HWPIX;
    #pragma unroll
    for (int j = 0; j < 4; ++j) {
        fc += __popc(fd[j]);
        oc += __popc(od[j]);
        if (od[j]) {
            const int bidx = __builtin_ctz(od[j]) >> 3;   // first opp byte in dword
            fo = min(fo, 16 * t + 4 * j + bidx);
        }
    }

    // ---- block reduction of counts / first-opp --------------------------
    #pragma unroll
    for (int off = 32; off > 0; off >>= 1) {
        fc += __shfl_down(fc, off);
        oc += __shfl_down(oc, off);
        fo  = min(fo, __shfl_down(fo, off));
    }
    if (lane == 0) { s_stat[wv][0] = fc; s_stat[wv][1] = oc; s_stat[wv][2] = fo; }
    __syncthreads();                          // also publishes s_food
    if (t == 0) {
        int nf = 0, no = 0, f = HWPIX;
        for (int wq = 0; wq < 4; ++wq) {
            nf += s_stat[wq][0]; no += s_stat[wq][1]; f = min(f, s_stat[wq][2]);
        }
        if (f == HWPIX) f = 0;                // argmax of all-False == 0
        s_hdr[0] = nf; s_hdr[1] = no; s_hdr[2] = f;
    }
    __syncthreads();
    const int n_food    = s_hdr[0];
    const int n_opp     = s_hdr[1];
    const int first_opp = s_hdr[2];
    const float orow = (float)(first_opp >> 6);
    const float ocol = (float)(first_opp & 63);

    // ---- Phase 2: two smallest food distances, first-argmin tiebreak ----
    float m1 = INFINITY, m2 = INFINITY;
    int   i1 = 0x7fffffff;
    #pragma unroll
    for (int k = 0; k < 16; ++k) {
        const int p = t + BLK * k;
        if (s_food[p]) {
            const float dr = (float)(p >> 6) - orow;
            const float dc = (float)(p & 63) - ocol;
            const float d  = sqrtf(dr * dr + dc * dc); // exact int squares; IEEE sqrt == numpy
            if (d < m1)      { m2 = m1; m1 = d; i1 = p; }
            else if (d < m2) { m2 = d; }               // d == m1 duplicate -> min2
        }
    }
    #pragma unroll
    for (int off = 32; off > 0; off >>= 1) {
        const float n1 = __shfl_down(m1, off);
        const int   j1 = __shfl_down(i1, off);
        const float n2 = __shfl_down(m2, off);
        if (n1 < m1 || (n1 == m1 && j1 < i1)) {
            m2 = fminf(m1, n2); m1 = n1; i1 = j1;
        } else {
            m2 = fminf(m2, n1);
        }
    }
    if (lane == 0) { s_m1[wv] = m1; s_m2[wv] = m2; s_i1[wv] = i1; }
    __syncthreads();

    // ---- decision on thread 0 ------------------------------------------
    if (t == 0) {
        m1 = s_m1[0]; m2 = s_m2[0]; i1 = s_i1[0];
        for (int wq = 1; wq < 4; ++wq) {
            const float n1 = s_m1[wq], n2 = s_m2[wq];
            const int   j1 = s_i1[wq];
            if (n1 < m1 || (n1 == m1 && j1 < i1)) {
                m2 = fminf(m1, n2); m1 = n1; i1 = j1;
            } else {
                m2 = fminf(m2, n1);
            }
        }
        const float diff = m2 - m1;  // only consumed when n_food > 1 (finite)
        const bool matches_start = (orow == opp_start[0]) && (ocol == opp_start[1]);
        const bool branchA   = (n_food > 1) && (n_opp > 0) && !matches_start;
        const bool ambiguous = (branchA && (diff < 0.1f)) || ((n_food > 1) && !branchA);
        const bool pick      = (branchA && (diff >= 0.1f)) || (n_food == 1);
        s_dec[0] = ambiguous ? 1 : 0;
        s_dec[1] = pick ? 1 : 0;
        s_dec[2] = i1;
    }
    __syncthreads();

    // ---- Phase 3: broadcast write, unit-stride float4 stores ------------
    const int amb = s_dec[0], pick = s_dec[1], midx = s_dec[2];
    const unsigned* s_food32 = (const unsigned*)s_food;
    float4* ob4 = (float4*)(out + (size_t)b * HWPIX);
    #pragma unroll
    for (int k = 0; k < 4; ++k) {
        const int kk = (k + b) & 3;
        const int q = t + BLK * kk;           // float4 index: pixels 4q..4q+3
        const unsigned fm = s_food32[q];      // 4 food bytes
        float4 r;
        float* rp = &r.x;
        #pragma unroll
        for (int i = 0; i < 4; ++i) {
            const int p = 4 * q + i;
            const bool f = (fm >> (8 * i)) & 0xFF;
            const float hit = amb ? (f ? 1.0f : 0.0f)
                                  : (pick ? ((p == midx) ? 1.0f : 0.0f) : 0.0f);
            rp[i] = -10.0f + 20.0f * hit;
        }
        ob4[q] = r;
    }
}

extern "C" void kernel_launch(void* const* d_in, const int* in_sizes, int n_in,
                              void* d_out, int out_size, void* d_ws, size_t ws_size,
                              hipStream_t stream) {
    const float* x         = (const float*)d_in[0];
    const float* opp_start = (const float*)d_in[1];
    float* out = (float*)d_out;
    const int B = in_sizes[0] / (HWPIX * 8);

    unsigned char* mask = (unsigned char*)d_ws;          // B*HWPIX bytes (16 MiB), ws is 2 GiB
    const long long n4 = (long long)B * HWPIX * 2;       // x as float4 entries

    compress_kernel<<<ABLOCKS, BLK, 0, stream>>>((const float4*)x, mask, n4);
    oracle_kernel<<<B, BLK, 0, stream>>>(mask, opp_start, out);
}

// Round 3
// 682.993 us; speedup vs baseline: 1.0636x; 1.0636x over previous
//
#include <hip/hip_runtime.h>
#include <math.h>

constexpr int HWPIX = 4096;   // 64*64 pixels per image
constexpr int BLK   = 256;

typedef float v4f __attribute__((ext_vector_type(4)));

__global__ __launch_bounds__(BLK) void oracle_kernel(
    const float* __restrict__ x,
    const float* __restrict__ opp_start,
    float* __restrict__ out)
{
    const int b    = blockIdx.x;
    const int t    = threadIdx.x;
    const int lane = t & 63;
    const int wv   = t >> 6;   // wave id 0..3

    // x for this image viewed as 8192 contiguous float4 entries;
    // entry 2p   = pixel p channels 0..3 (ch1=[1] food, ch3=[3] opp)
    // entry 2p+1 = pixel p channels 4..7 (never needed)
    const v4f* xb = (const v4f*)(x + (size_t)b * HWPIX * 8);

    __shared__ unsigned char s_food[HWPIX];  // 4 KiB byte mask
    __shared__ int   s_stat[4][3];           // per-wave: food_cnt, opp_cnt, first_opp
    __shared__ float s_m1[4], s_m2[4];
    __shared__ int   s_i1[4];
    __shared__ int   s_hdr[3];               // n_food, n_opp, first_opp
    __shared__ int   s_dec[3];               // ambiguous, pick_nearest, min_idx

    // ---- Phase 1: UNIT-STRIDE stream of all of x, NON-TEMPORAL ---------
    // NT theory: every timed iteration starts right after a 2 GiB poison
    // fill that leaves the whole 256 MiB LLC full of DIRTY lines. A normal
    // read miss must evict a dirty victim (writeback) before allocating,
    // and the read stream serializes behind the victim/writeback path --
    // three structurally different kernels all measured ~1.5-1.7 TB/s on
    // this read while the write fill does 6.4 TB/s. x has zero reuse
    // (each byte read once/iter, 512 MiB > LLC), so NT loads (no LLC
    // allocation -> no eviction -> no writeback on the read path) should
    // stream at fill-like rates.
    const bool even  = (t & 1) == 0;
    const int  pbase = t >> 1;               // pixel owned by even thread at j=0
    int fc = 0, oc = 0, fo = HWPIX;

    #pragma unroll
    for (int jo = 0; jo < 32; jo += 8) {
        v4f v[8];
        #pragma unroll
        for (int ji = 0; ji < 8; ++ji)
            v[ji] = __builtin_nontemporal_load(&xb[t + BLK * (jo + ji)]);
        #pragma unroll
        for (int ji = 0; ji < 8; ++ji) {
            const int  p    = pbase + 128 * (jo + ji);
            const bool food = (v[ji][1] == 1.0f);
            const bool opp  = (v[ji][3] == 1.0f);
            if (even) {
                s_food[p] = food ? 1 : 0;
                fc += food ? 1 : 0;
                oc += opp  ? 1 : 0;
                fo  = opp ? min(fo, p) : fo;
            }
        }
    }

    // ---- block reduction of counts / first-opp (odd threads contribute 0)
    #pragma unroll
    for (int off = 32; off > 0; off >>= 1) {
        fc += __shfl_down(fc, off);
        oc += __shfl_down(oc, off);
        fo  = min(fo, __shfl_down(fo, off));
    }
    if (lane == 0) { s_stat[wv][0] = fc; s_stat[wv][1] = oc; s_stat[wv][2] = fo; }
    __syncthreads();                          // also publishes s_food
    if (t == 0) {
        int nf = 0, no = 0, f = HWPIX;
        for (int w = 0; w < 4; ++w) {
            nf += s_stat[w][0]; no += s_stat[w][1]; f = min(f, s_stat[w][2]);
        }
        if (f == HWPIX) f = 0;                // argmax of all-False == 0
        s_hdr[0] = nf; s_hdr[1] = no; s_hdr[2] = f;
    }
    __syncthreads();
    const int n_food    = s_hdr[0];
    const int n_opp     = s_hdr[1];
    const int first_opp = s_hdr[2];
    const float orow = (float)(first_opp >> 6);
    const float ocol = (float)(first_opp & 63);

    // ---- Phase 2: two smallest food distances, first-argmin tiebreak ----
    float m1 = INFINITY, m2 = INFINITY;
    int   i1 = 0x7fffffff;
    #pragma unroll
    for (int k = 0; k < 16; ++k) {
        const int p = t + BLK * k;
        if (s_food[p]) {
            const float dr = (float)(p >> 6) - orow;
            const float dc = (float)(p & 63) - ocol;
            const float d  = sqrtf(dr * dr + dc * dc); // exact int squares; IEEE sqrt == numpy
            if (d < m1)      { m2 = m1; m1 = d; i1 = p; }
            else if (d < m2) { m2 = d; }               // d == m1 duplicate -> min2
        }
    }
    #pragma unroll
    for (int off = 32; off > 0; off >>= 1) {
        const float n1 = __shfl_down(m1, off);
        const int   j1 = __shfl_down(i1, off);
        const float n2 = __shfl_down(m2, off);
        if (n1 < m1 || (n1 == m1 && j1 < i1)) {
            m2 = fminf(m1, n2); m1 = n1; i1 = j1;
        } else {
            m2 = fminf(m2, n1);
        }
    }
    if (lane == 0) { s_m1[wv] = m1; s_m2[wv] = m2; s_i1[wv] = i1; }
    __syncthreads();

    // ---- decision on thread 0 ------------------------------------------
    if (t == 0) {
        m1 = s_m1[0]; m2 = s_m2[0]; i1 = s_i1[0];
        for (int w = 1; w < 4; ++w) {
            const float n1 = s_m1[w], n2 = s_m2[w];
            const int   j1 = s_i1[w];
            if (n1 < m1 || (n1 == m1 && j1 < i1)) {
                m2 = fminf(m1, n2); m1 = n1; i1 = j1;
            } else {
                m2 = fminf(m2, n1);
            }
        }
        const float diff = m2 - m1;  // only consumed when n_food > 1 (finite)
        const bool matches_start = (orow == opp_start[0]) && (ocol == opp_start[1]);
        const bool branchA   = (n_food > 1) && (n_opp > 0) && !matches_start;
        const bool ambiguous = (branchA && (diff < 0.1f)) || ((n_food > 1) && !branchA);
        const bool pick      = (branchA && (diff >= 0.1f)) || (n_food == 1);
        s_dec[0] = ambiguous ? 1 : 0;
        s_dec[1] = pick ? 1 : 0;
        s_dec[2] = i1;
    }
    __syncthreads();

    // ---- Phase 3: broadcast write, unit-stride float4 stores ------------
    const int amb = s_dec[0], pick = s_dec[1], midx = s_dec[2];
    const unsigned* s_food32 = (const unsigned*)s_food;
    float4* ob4 = (float4*)(out + (size_t)b * HWPIX);
    #pragma unroll
    for (int k = 0; k < 4; ++k) {
        const int q = t + BLK * k;            // float4 index: pixels 4q..4q+3
        const unsigned fm = s_food32[q];      // 4 food bytes
        float4 r;
        float* rp = &r.x;
        #pragma unroll
        for (int i = 0; i < 4; ++i) {
            const int p = 4 * q + i;
            const bool f = (fm >> (8 * i)) & 0xFF;
            const float hit = amb ? (f ? 1.0f : 0.0f)
                                  : (pick ? ((p == midx) ? 1.0f : 0.0f) : 0.0f);
            rp[i] = -10.0f + 20.0f * hit;
        }
        ob4[q] = r;
    }
}

extern "C" void kernel_launch(void* const* d_in, const int* in_sizes, int n_in,
                              void* d_out, int out_size, void* d_ws, size_t ws_size,
                              hipStream_t stream) {
    const float* x         = (const float*)d_in[0];
    const float* opp_start = (const float*)d_in[1];
    float* out = (float*)d_out;
    const int B = in_sizes[0] / (HWPIX * 8);
    oracle_kernel<<<B, BLK, 0, stream>>>(x, opp_start, out);
}